// Round 6
// baseline (468.330 us; speedup 1.0000x reference)
//
#include <hip/hip_runtime.h>
#include <hip/hip_bf16.h>
#include <stdint.h>

#define NB 8
#define NSEQ 1024
#define DIMM 768
#define NHEADS 12
#define DH 64
#define NQKV 2304
#define ALPHA_ 0.25f
#define SCALE_ 0.125f
#define EPS_ 1e-5f

typedef __bf16 bf16;
typedef bf16 bf16x8 __attribute__((ext_vector_type(8)));
typedef bf16 bf16x4 __attribute__((ext_vector_type(4)));
typedef float f32x4 __attribute__((ext_vector_type(4)));

#define MFMA16(a, b, c) __builtin_amdgcn_mfma_f32_16x16x32_bf16((a), (b), (c), 0, 0, 0)

static __device__ __forceinline__ void load_lds16(const void* gsrc, void* ldst) {
  __builtin_amdgcn_global_load_lds(
      (__attribute__((address_space(1))) void*)gsrc,
      (__attribute__((address_space(3))) void*)ldst, 16, 0, 0);
}

// ---------------- LayerNorm + bf16 cast: x(8192x768) -> xn bf16 ----------------
__global__ __launch_bounds__(256) void ln_kernel(
    const float* __restrict__ x, const float* __restrict__ gamma,
    const float* __restrict__ beta, bf16* __restrict__ xn) {
  const int row = blockIdx.x * 4 + (threadIdx.x >> 6);
  const int lane = threadIdx.x & 63;
  const float* xr = x + (size_t)row * DIMM;
  float4 v[3];
  float s = 0.f, s2 = 0.f;
#pragma unroll
  for (int c = 0; c < 3; ++c) {
    v[c] = *reinterpret_cast<const float4*>(xr + c * 256 + lane * 4);
    s += v[c].x + v[c].y + v[c].z + v[c].w;
    s2 += v[c].x * v[c].x + v[c].y * v[c].y + v[c].z * v[c].z + v[c].w * v[c].w;
  }
#pragma unroll
  for (int m = 1; m < 64; m <<= 1) {
    s += __shfl_xor(s, m);
    s2 += __shfl_xor(s2, m);
  }
  const float mu = s * (1.f / DIMM);
  const float rstd = rsqrtf(s2 * (1.f / DIMM) - mu * mu + EPS_);
#pragma unroll
  for (int c = 0; c < 3; ++c) {
    const float4 g4 = *reinterpret_cast<const float4*>(gamma + c * 256 + lane * 4);
    const float4 b4 = *reinterpret_cast<const float4*>(beta + c * 256 + lane * 4);
    bf16x4 o;
    o[0] = (bf16)((v[c].x - mu) * rstd * g4.x + b4.x);
    o[1] = (bf16)((v[c].y - mu) * rstd * g4.y + b4.y);
    o[2] = (bf16)((v[c].z - mu) * rstd * g4.z + b4.z);
    o[3] = (bf16)((v[c].w - mu) * rstd * g4.w + b4.w);
    *reinterpret_cast<bf16x4*>(xn + (size_t)row * DIMM + c * 256 + lane * 4) = o;
  }
}

// ------------- transpose + cast: f32 in[R][C] -> bf16 out[C][R] -------------
__global__ __launch_bounds__(256) void tcast_kernel(
    const float* __restrict__ in, bf16* __restrict__ out, int R, int C) {
  __shared__ float tile[32][33];
  const int tx = threadIdx.x & 31, ty = threadIdx.x >> 5;
  const int c0 = blockIdx.x * 32, r0 = blockIdx.y * 32;
#pragma unroll
  for (int i = ty; i < 32; i += 8)
    tile[i][tx] = in[(size_t)(r0 + i) * C + c0 + tx];
  __syncthreads();
#pragma unroll
  for (int i = ty; i < 32; i += 8)
    out[(size_t)(c0 + i) * R + r0 + tx] = (bf16)tile[tx][i];
}

// -------- QKV GEMM: xn(8192x768) @ wT(2304 cols x 768 k) -> q,k,vT bf16 --------
__global__ __launch_bounds__(256) void qkv_gemm(
    const bf16* __restrict__ xn, const bf16* __restrict__ wT,
    bf16* __restrict__ qb, bf16* __restrict__ kb, bf16* __restrict__ vt) {
  __shared__ __align__(16) bf16 As[128 * 32];
  __shared__ __align__(16) bf16 Bs[64 * 32];
  const int tid = threadIdx.x;
  const int wv = tid >> 6, l = tid & 63;
  const int l16 = l & 15, q4 = l >> 4;
  const int c0 = blockIdx.x * 64, row0 = blockIdx.y * 128;
  const int sr = tid >> 2, skk = (tid & 3) * 8;
  f32x4 acc0[4], acc1[4];
#pragma unroll
  for (int c = 0; c < 4; ++c) {
    acc0[c] = f32x4{0.f, 0.f, 0.f, 0.f};
    acc1[c] = f32x4{0.f, 0.f, 0.f, 0.f};
  }
  for (int k0 = 0; k0 < DIMM; k0 += 32) {
    __syncthreads();
    load_lds16(xn + (size_t)(row0 + sr) * DIMM + k0 + skk, As + tid * 8);
    load_lds16(xn + (size_t)(row0 + 64 + sr) * DIMM + k0 + skk, As + 2048 + tid * 8);
    load_lds16(wT + (size_t)(c0 + sr) * DIMM + k0 + skk, Bs + tid * 8);
    __syncthreads();
    const bf16x8 a0 = *reinterpret_cast<const bf16x8*>(&As[(wv * 32 + l16) * 32 + q4 * 8]);
    const bf16x8 a1 = *reinterpret_cast<const bf16x8*>(&As[(wv * 32 + 16 + l16) * 32 + q4 * 8]);
#pragma unroll
    for (int c = 0; c < 4; ++c) {
      const bf16x8 bb = *reinterpret_cast<const bf16x8*>(&Bs[(c * 16 + l16) * 32 + q4 * 8]);
      acc0[c] = MFMA16(a0, bb, acc0[c]);
      acc1[c] = MFMA16(a1, bb, acc1[c]);
    }
  }
  const int sect = c0 / DIMM;          // 0=q 1=k 2=v (uniform per block)
  const int head = (c0 % DIMM) >> 6;   // uniform per block
#pragma unroll
  for (int c = 0; c < 4; ++c) {
    const int dd = c * 16 + l16;
#pragma unroll
    for (int r = 0; r < 4; ++r) {
#pragma unroll
      for (int rsub = 0; rsub < 2; ++rsub) {
        const int gm = row0 + wv * 32 + rsub * 16 + q4 * 4 + r;
        const int b = gm >> 10, n = gm & 1023;
        const size_t bhh = (size_t)b * NHEADS + head;
        const float av = rsub ? acc1[c][r] : acc0[c][r];
        const bf16 val = (bf16)av;
        if (sect == 0)      qb[(bhh * NSEQ + n) * DH + dd] = val;
        else if (sect == 1) kb[(bhh * NSEQ + n) * DH + dd] = val;
        else                vt[(bhh * DH + dd) * NSEQ + n] = val;
      }
    }
  }
}

// -------- fused attention: swapped-operand MFMA, lane-aligned softmax --------
// Block: 16 Q-rows (one bh), 4 waves; wave wv owns j in [wv*256, wv*256+256),
// processed as 4 sub-tiles of 64 cols. QK^T computed as mfma(K, Q^T) so lane
// (l16,q4) holds S[q=l16][j=q4*4+r+16js]: h/blended are direct float4 reg
// accesses (no LDS), softmax stats are lane-scalar, PV = mfma(V^T, P^T) gives
// out^T whose layout is also q=l16 (rescale needs no shuffles). P goes through
// a tiny wave-private LDS repack (4x ds_write_b64 + 2x ds_read_b128 per st).
// Zero barriers in the main loop; 2 __syncthreads in the cross-wave merge.
__global__ __launch_bounds__(256, 4) void attn_kernel(
    const bf16* __restrict__ qb, const bf16* __restrict__ kb,
    const bf16* __restrict__ vt, const float* __restrict__ h,
    float* __restrict__ blended, bf16* __restrict__ attn_out) {
  __shared__ __align__(16) bf16 pw_all[4][16][80];   // 10240 B
  __shared__ __align__(16) float ored[4][16][68];    // 17408 B
  __shared__ float wred_m[4][16];
  __shared__ float wred_l[4][16];

  const int tid = threadIdx.x;
  const int wv = tid >> 6, l = tid & 63;
  const int l16 = l & 15, q4 = l >> 4;
  const int i0 = blockIdx.x * 16;
  const int bh = blockIdx.y;
  const int jb = wv * 256;

  const float* hq = h + ((size_t)bh << 20) + (size_t)(i0 + l16) * NSEQ + jb + q4 * 4;
  float* bq = blended + ((size_t)bh << 20) + (size_t)(i0 + l16) * NSEQ + jb + q4 * 4;
  const bf16* kq = kb + ((size_t)bh * NSEQ + jb + l16) * DH + q4 * 8;
  const bf16* vq = vt + ((size_t)bh * DH + l16) * NSEQ + jb + q4 * 8;
  bf16(*pw)[80] = pw_all[wv];

  // Q^T fragments: Q[i0+l16][w2*32 + q4*8 .. +7]
  bf16x8 qT[2];
#pragma unroll
  for (int w2 = 0; w2 < 2; ++w2)
    qT[w2] = *reinterpret_cast<const bf16x8*>(
        qb + ((size_t)bh * NSEQ + i0 + l16) * DH + w2 * 32 + q4 * 8);

  float m_run = -1e30f, l_run = 0.f;
  f32x4 acc[4];
#pragma unroll
  for (int f = 0; f < 4; ++f) acc[f] = f32x4{0.f, 0.f, 0.f, 0.f};

  float4 hvA[4], hvB[4];
#pragma unroll
  for (int js = 0; js < 4; ++js)
    hvA[js] = *reinterpret_cast<const float4*>(hq + js * 16);

  auto BODY = [&](int st, float4* hcur, float4* hnext, bool pf) {
    // QK^T: S[q=l16][j] via mfma(K, Q^T)
    f32x4 s[4];
#pragma unroll
    for (int js = 0; js < 4; ++js) s[js] = f32x4{0.f, 0.f, 0.f, 0.f};
#pragma unroll
    for (int js = 0; js < 4; ++js) {
#pragma unroll
      for (int w2 = 0; w2 < 2; ++w2) {
        const bf16x8 kf = *reinterpret_cast<const bf16x8*>(
            kq + (size_t)(st * 64 + js * 16) * DH + w2 * 32);
        s[js] = MFMA16(kf, qT[w2], s[js]);
      }
    }
    // prefetch next sub-tile's h (compiler-tracked reg dependence)
    if (pf) {
#pragma unroll
      for (int js = 0; js < 4; ++js)
        hnext[js] = *reinterpret_cast<const float4*>(hq + (st + 1) * 64 + js * 16);
    }
    // blend + blended store + strip max
    float tm = -1e30f;
#pragma unroll
    for (int js = 0; js < 4; ++js) {
      float4 b;
      b.x = s[js][0] * (ALPHA_ * SCALE_) + 0.75f * hcur[js].x;
      b.y = s[js][1] * (ALPHA_ * SCALE_) + 0.75f * hcur[js].y;
      b.z = s[js][2] * (ALPHA_ * SCALE_) + 0.75f * hcur[js].z;
      b.w = s[js][3] * (ALPHA_ * SCALE_) + 0.75f * hcur[js].w;
      *reinterpret_cast<float4*>(bq + st * 64 + js * 16) = b;
      s[js][0] = b.x; s[js][1] = b.y; s[js][2] = b.z; s[js][3] = b.w;
      tm = fmaxf(tm, fmaxf(fmaxf(b.x, b.y), fmaxf(b.z, b.w)));
    }
    // row max across the 4 q4-lanes holding this q-row
    tm = fmaxf(tm, __shfl_xor(tm, 16));
    tm = fmaxf(tm, __shfl_xor(tm, 32));
    const float mnew = fmaxf(m_run, tm);
    const float sc = __expf(m_run - mnew);
    m_run = mnew;
    l_run *= sc;
#pragma unroll
    for (int f = 0; f < 4; ++f) acc[f] *= sc;
    // P = exp(blended - m), packed bf16x4 writes to wave-private LDS
    float rs = 0.f;
#pragma unroll
    for (int js = 0; js < 4; ++js) {
      bf16x4 pk;
#pragma unroll
      for (int r = 0; r < 4; ++r) {
        const float p = __expf(s[js][r] - mnew);
        rs += p;
        pk[r] = (bf16)p;
      }
      *reinterpret_cast<bf16x4*>(&pw[l16][js * 16 + q4 * 4]) = pk;
    }
    rs += __shfl_xor(rs, 16);
    rs += __shfl_xor(rs, 32);
    l_run += rs;
    // PV: out^T += mfma(V^T, P^T)
    bf16x8 pa[2];
#pragma unroll
    for (int w2 = 0; w2 < 2; ++w2)
      pa[w2] = *reinterpret_cast<const bf16x8*>(&pw[l16][w2 * 32 + q4 * 8]);
#pragma unroll
    for (int f = 0; f < 4; ++f) {
#pragma unroll
      for (int w2 = 0; w2 < 2; ++w2) {
        const bf16x8 vf = *reinterpret_cast<const bf16x8*>(
            vq + (size_t)(f * 16) * NSEQ + st * 64 + w2 * 32);
        acc[f] = MFMA16(vf, pa[w2], acc[f]);
      }
    }
  };

  BODY(0, hvA, hvB, true);
  BODY(1, hvB, hvA, true);
  BODY(2, hvA, hvB, true);
  BODY(3, hvB, hvA, false);

  // ---- epilogue: merge wave-local (m,l,acc) across the 4 waves ----
  if (q4 == 0) {
    wred_m[wv][l16] = m_run;
    wred_l[wv][l16] = l_run;
  }
  __syncthreads();
  float ms = -1e30f;
#pragma unroll
  for (int w = 0; w < 4; ++w) ms = fmaxf(ms, wred_m[w][l16]);
  float ls = 0.f;
#pragma unroll
  for (int w = 0; w < 4; ++w) ls += wred_l[w][l16] * __expf(wred_m[w][l16] - ms);
  const float osc = __expf(m_run - ms) / ls;
#pragma unroll
  for (int f = 0; f < 4; ++f) {
    f32x4 sv = acc[f] * osc;
    *reinterpret_cast<f32x4*>(&ored[wv][l16][f * 16 + q4 * 4]) = sv;
  }
  __syncthreads();
  const int b = bh / NHEADS, head = bh % NHEADS;
#pragma unroll
  for (int m = 0; m < 4; ++m) {
    float4 o = *reinterpret_cast<const float4*>(&ored[0][l16][q4 * 16 + 4 * m]);
#pragma unroll
    for (int w = 1; w < 4; ++w) {
      const float4 t = *reinterpret_cast<const float4*>(&ored[w][l16][q4 * 16 + 4 * m]);
      o.x += t.x; o.y += t.y; o.z += t.z; o.w += t.w;
    }
    bf16x4 ov;
    ov[0] = (bf16)o.x; ov[1] = (bf16)o.y; ov[2] = (bf16)o.z; ov[3] = (bf16)o.w;
    *reinterpret_cast<bf16x4*>(
        attn_out + ((size_t)b * NSEQ + i0 + l16) * DIMM + head * DH + q4 * 16 + 4 * m) = ov;
  }
}

// -------- output projection: attn_out(8192x768) @ woutT + b_out -> f32 out --------
__global__ __launch_bounds__(256) void oproj_gemm(
    const bf16* __restrict__ ain, const bf16* __restrict__ wT,
    const float* __restrict__ bias, float* __restrict__ out) {
  __shared__ __align__(16) bf16 As[128 * 32];
  __shared__ __align__(16) bf16 Bs[64 * 32];
  const int tid = threadIdx.x;
  const int wv = tid >> 6, l = tid & 63;
  const int l16 = l & 15, q4 = l >> 4;
  const int c0 = blockIdx.x * 64, row0 = blockIdx.y * 128;
  const int sr = tid >> 2, skk = (tid & 3) * 8;
  f32x4 acc0[4], acc1[4];
#pragma unroll
  for (int c = 0; c < 4; ++c) {
    acc0[c] = f32x4{0.f, 0.f, 0.f, 0.f};
    acc1[c] = f32x4{0.f, 0.f, 0.f, 0.f};
  }
  for (int k0 = 0; k0 < DIMM; k0 += 32) {
    __syncthreads();
    load_lds16(ain + (size_t)(row0 + sr) * DIMM + k0 + skk, As + tid * 8);
    load_lds16(ain + (size_t)(row0 + 64 + sr) * DIMM + k0 + skk, As + 2048 + tid * 8);
    load_lds16(wT + (size_t)(c0 + sr) * DIMM + k0 + skk, Bs + tid * 8);
    __syncthreads();
    const bf16x8 a0 = *reinterpret_cast<const bf16x8*>(&As[(wv * 32 + l16) * 32 + q4 * 8]);
    const bf16x8 a1 = *reinterpret_cast<const bf16x8*>(&As[(wv * 32 + 16 + l16) * 32 + q4 * 8]);
#pragma unroll
    for (int c = 0; c < 4; ++c) {
      const bf16x8 bb = *reinterpret_cast<const bf16x8*>(&Bs[(c * 16 + l16) * 32 + q4 * 8]);
      acc0[c] = MFMA16(a0, bb, acc0[c]);
      acc1[c] = MFMA16(a1, bb, acc1[c]);
    }
  }
#pragma unroll
  for (int c = 0; c < 4; ++c) {
    const int gc = c0 + c * 16 + l16;
    const float bv = bias[gc];
#pragma unroll
    for (int r = 0; r < 4; ++r) {
      out[(size_t)(row0 + wv * 32 + q4 * 4 + r) * DIMM + gc] = acc0[c][r] + bv;
      out[(size_t)(row0 + wv * 32 + 16 + q4 * 4 + r) * DIMM + gc] = acc1[c][r] + bv;
    }
  }
}

extern "C" void kernel_launch(void* const* d_in, const int* in_sizes, int n_in,
                              void* d_out, int out_size, void* d_ws, size_t ws_size,
                              hipStream_t stream) {
  const float* x = (const float*)d_in[0];
  const float* h = (const float*)d_in[1];
  const float* gamma = (const float*)d_in[2];
  const float* beta = (const float*)d_in[3];
  const float* w_qkv = (const float*)d_in[4];
  const float* w_out = (const float*)d_in[5];
  const float* b_out = (const float*)d_in[6];
  float* out = (float*)d_out;
  float* blended = out + (size_t)NB * NSEQ * DIMM;

  char* ws = (char*)d_ws;
  bf16* xn = (bf16*)(ws);                   // 12.6 MB; reused as attn_out after qkv_gemm
  bf16* qb = (bf16*)(ws + 12582912);
  bf16* kb = (bf16*)(ws + 25165824);
  bf16* vt = (bf16*)(ws + 37748736);
  bf16* wqkvT = (bf16*)(ws + 50331648);
  bf16* woutT = (bf16*)(ws + 53870592);

  hipLaunchKernelGGL(ln_kernel, dim3(2048), dim3(256), 0, stream, x, gamma, beta, xn);
  hipLaunchKernelGGL(tcast_kernel, dim3(72, 24), dim3(256), 0, stream, w_qkv, wqkvT, DIMM, NQKV);
  hipLaunchKernelGGL(tcast_kernel, dim3(24, 24), dim3(256), 0, stream, w_out, woutT, DIMM, DIMM);
  hipLaunchKernelGGL(qkv_gemm, dim3(36, 64), dim3(256), 0, stream, xn, wqkvT, qb, kb, vt);
  hipLaunchKernelGGL(attn_kernel, dim3(64, 96), dim3(256), 0, stream, qb, kb, vt, h, blended, xn);
  hipLaunchKernelGGL(oproj_gemm, dim3(12, 64), dim3(256), 0, stream, xn, woutT, b_out, out);
}

// Round 7
// 386.982 us; speedup vs baseline: 1.2102x; 1.2102x over previous
//
#include <hip/hip_runtime.h>
#include <hip/hip_bf16.h>
#include <stdint.h>

#define NB 8
#define NSEQ 1024
#define DIMM 768
#define NHEADS 12
#define DH 64
#define NQKV 2304
#define ALPHA_ 0.25f
#define SCALE_ 0.125f
#define EPS_ 1e-5f

typedef __bf16 bf16;
typedef bf16 bf16x8 __attribute__((ext_vector_type(8)));
typedef bf16 bf16x4 __attribute__((ext_vector_type(4)));
typedef float f32x4 __attribute__((ext_vector_type(4)));

#define MFMA16(a, b, c) __builtin_amdgcn_mfma_f32_16x16x32_bf16((a), (b), (c), 0, 0, 0)

static __device__ __forceinline__ void load_lds16(const void* gsrc, void* ldst) {
  __builtin_amdgcn_global_load_lds(
      (__attribute__((address_space(1))) void*)gsrc,
      (__attribute__((address_space(3))) void*)ldst, 16, 0, 0);
}

// lgkm-only barrier (does NOT drain vmcnt -> in-flight global loads survive)
#define BAR_LGKM()                                             \
  do {                                                         \
    __builtin_amdgcn_sched_barrier(0);                         \
    asm volatile("s_waitcnt lgkmcnt(0)" ::: "memory");         \
    __builtin_amdgcn_s_barrier();                              \
    __builtin_amdgcn_sched_barrier(0);                         \
  } while (0)

// LDS byte-offset swizzle: XOR bits[6:4] with (row&7) ^ colbyte bits[9:7].
// Keeps bits[3:0] (8B/16B alignment). Verified per-phase: all accesses <=2-way.
static __device__ __forceinline__ int swz(int row, int cb) {
  return cb ^ ((((row & 7) ^ ((cb >> 7) & 7)) << 4));
}

// ---------------- LayerNorm + bf16 cast: x(8192x768) -> xn bf16 ----------------
__global__ __launch_bounds__(256) void ln_kernel(
    const float* __restrict__ x, const float* __restrict__ gamma,
    const float* __restrict__ beta, bf16* __restrict__ xn) {
  const int row = blockIdx.x * 4 + (threadIdx.x >> 6);
  const int lane = threadIdx.x & 63;
  const float* xr = x + (size_t)row * DIMM;
  float4 v[3];
  float s = 0.f, s2 = 0.f;
#pragma unroll
  for (int c = 0; c < 3; ++c) {
    v[c] = *reinterpret_cast<const float4*>(xr + c * 256 + lane * 4);
    s += v[c].x + v[c].y + v[c].z + v[c].w;
    s2 += v[c].x * v[c].x + v[c].y * v[c].y + v[c].z * v[c].z + v[c].w * v[c].w;
  }
#pragma unroll
  for (int m = 1; m < 64; m <<= 1) {
    s += __shfl_xor(s, m);
    s2 += __shfl_xor(s2, m);
  }
  const float mu = s * (1.f / DIMM);
  const float rstd = rsqrtf(s2 * (1.f / DIMM) - mu * mu + EPS_);
#pragma unroll
  for (int c = 0; c < 3; ++c) {
    const float4 g4 = *reinterpret_cast<const float4*>(gamma + c * 256 + lane * 4);
    const float4 b4 = *reinterpret_cast<const float4*>(beta + c * 256 + lane * 4);
    bf16x4 o;
    o[0] = (bf16)((v[c].x - mu) * rstd * g4.x + b4.x);
    o[1] = (bf16)((v[c].y - mu) * rstd * g4.y + b4.y);
    o[2] = (bf16)((v[c].z - mu) * rstd * g4.z + b4.z);
    o[3] = (bf16)((v[c].w - mu) * rstd * g4.w + b4.w);
    *reinterpret_cast<bf16x4*>(xn + (size_t)row * DIMM + c * 256 + lane * 4) = o;
  }
}

// ------------- transpose + cast: f32 in[R][C] -> bf16 out[C][R] -------------
__global__ __launch_bounds__(256) void tcast_kernel(
    const float* __restrict__ in, bf16* __restrict__ out, int R, int C) {
  __shared__ float tile[32][33];
  const int tx = threadIdx.x & 31, ty = threadIdx.x >> 5;
  const int c0 = blockIdx.x * 32, r0 = blockIdx.y * 32;
#pragma unroll
  for (int i = ty; i < 32; i += 8)
    tile[i][tx] = in[(size_t)(r0 + i) * C + c0 + tx];
  __syncthreads();
#pragma unroll
  for (int i = ty; i < 32; i += 8)
    out[(size_t)(c0 + i) * R + r0 + tx] = (bf16)tile[tx][i];
}

// -------- QKV GEMM: xn(8192x768) @ wT(2304 cols x 768 k) -> q,k,vT bf16 --------
__global__ __launch_bounds__(256) void qkv_gemm(
    const bf16* __restrict__ xn, const bf16* __restrict__ wT,
    bf16* __restrict__ qb, bf16* __restrict__ kb, bf16* __restrict__ vt) {
  __shared__ __align__(16) bf16 As[128 * 32];
  __shared__ __align__(16) bf16 Bs[64 * 32];
  const int tid = threadIdx.x;
  const int wv = tid >> 6, l = tid & 63;
  const int l16 = l & 15, q4 = l >> 4;
  const int c0 = blockIdx.x * 64, row0 = blockIdx.y * 128;
  const int sr = tid >> 2, skk = (tid & 3) * 8;
  f32x4 acc0[4], acc1[4];
#pragma unroll
  for (int c = 0; c < 4; ++c) {
    acc0[c] = f32x4{0.f, 0.f, 0.f, 0.f};
    acc1[c] = f32x4{0.f, 0.f, 0.f, 0.f};
  }
  for (int k0 = 0; k0 < DIMM; k0 += 32) {
    __syncthreads();
    load_lds16(xn + (size_t)(row0 + sr) * DIMM + k0 + skk, As + tid * 8);
    load_lds16(xn + (size_t)(row0 + 64 + sr) * DIMM + k0 + skk, As + 2048 + tid * 8);
    load_lds16(wT + (size_t)(c0 + sr) * DIMM + k0 + skk, Bs + tid * 8);
    __syncthreads();
    const bf16x8 a0 = *reinterpret_cast<const bf16x8*>(&As[(wv * 32 + l16) * 32 + q4 * 8]);
    const bf16x8 a1 = *reinterpret_cast<const bf16x8*>(&As[(wv * 32 + 16 + l16) * 32 + q4 * 8]);
#pragma unroll
    for (int c = 0; c < 4; ++c) {
      const bf16x8 bb = *reinterpret_cast<const bf16x8*>(&Bs[(c * 16 + l16) * 32 + q4 * 8]);
      acc0[c] = MFMA16(a0, bb, acc0[c]);
      acc1[c] = MFMA16(a1, bb, acc1[c]);
    }
  }
  const int sect = c0 / DIMM;          // 0=q 1=k 2=v (uniform per block)
  const int head = (c0 % DIMM) >> 6;   // uniform per block
#pragma unroll
  for (int c = 0; c < 4; ++c) {
    const int dd = c * 16 + l16;
#pragma unroll
    for (int r = 0; r < 4; ++r) {
#pragma unroll
      for (int rsub = 0; rsub < 2; ++rsub) {
        const int gm = row0 + wv * 32 + rsub * 16 + q4 * 4 + r;
        const int b = gm >> 10, n = gm & 1023;
        const size_t bhh = (size_t)b * NHEADS + head;
        const float av = rsub ? acc1[c][r] : acc0[c][r];
        const bf16 val = (bf16)av;
        if (sect == 0)      qb[(bhh * NSEQ + n) * DH + dd] = val;
        else if (sect == 1) kb[(bhh * NSEQ + n) * DH + dd] = val;
        else                vt[(bhh * DH + dd) * NSEQ + n] = val;
      }
    }
  }
}

// -------- fused attention, 3-phase: MFMA -> memcpy-shaped stream -> PV --------
// Block: 16 q-rows x full 1024 j, 4 waves.
// P1: S=QK^T (swapped operands) -> bf16 swizzled LDS [16][1088]; wave owns a
//     256-col strip for all 16 rows.
// P2: wave owns 4 FULL rows; h read / blended write in contiguous 1KB bursts
//     (m13 copy shape); EXACT per-row softmax (no online rescale, no merge);
//     P overwrites S in LDS.
// P3: out = P @ V^T from LDS/L2; normalize by exact row sum.
__global__ __launch_bounds__(256, 4) void attn_kernel(
    const bf16* __restrict__ qb, const bf16* __restrict__ kb,
    const bf16* __restrict__ vt, const float* __restrict__ h,
    float* __restrict__ blended, bf16* __restrict__ attn_out) {
  __shared__ __align__(16) char S_lds[16 * 2176];  // bf16 [16][1088], swizzled
  __shared__ float lred[16];

  const int tid = threadIdx.x;
  const int wv = tid >> 6, l = tid & 63;
  const int l16 = l & 15, q4 = l >> 4;
  const int i0 = blockIdx.x * 16;
  const int bh = blockIdx.y;
  const int jb = wv * 256;

  const float* hbase = h + ((size_t)bh << 20);
  float* bbase = blended + ((size_t)bh << 20);

  // Q^T fragments
  bf16x8 qT[2];
#pragma unroll
  for (int w2 = 0; w2 < 2; ++w2)
    qT[w2] = *reinterpret_cast<const bf16x8*>(
        qb + ((size_t)bh * NSEQ + i0 + l16) * DH + w2 * 32 + q4 * 8);

  // prefetch h rows wv*4+0,1 (consumed in Phase 2, hidden under Phase 1)
  float4 hv0[4], hv1[4];
#pragma unroll
  for (int t = 0; t < 4; ++t) {
    hv0[t] = *reinterpret_cast<const float4*>(
        hbase + (size_t)(i0 + wv * 4 + 0) * NSEQ + t * 256 + l * 4);
    hv1[t] = *reinterpret_cast<const float4*>(
        hbase + (size_t)(i0 + wv * 4 + 1) * NSEQ + t * 256 + l * 4);
  }

  // ---- Phase 1: S(scaled) -> LDS bf16, swizzled ----
  const bf16* kq = kb + ((size_t)bh * NSEQ + jb + l16) * DH + q4 * 8;
  char* srow_w = S_lds + l16 * 2176;
#pragma unroll
  for (int st = 0; st < 4; ++st) {
    f32x4 s[4];
#pragma unroll
    for (int js = 0; js < 4; ++js) s[js] = f32x4{0.f, 0.f, 0.f, 0.f};
#pragma unroll
    for (int js = 0; js < 4; ++js) {
#pragma unroll
      for (int w2 = 0; w2 < 2; ++w2) {
        const bf16x8 kf = *reinterpret_cast<const bf16x8*>(
            kq + (size_t)(st * 64 + js * 16) * DH + w2 * 32);
        s[js] = MFMA16(kf, qT[w2], s[js]);
      }
    }
    // lane (l16,q4) holds S[q=l16][j=jb+st*64+js*16+q4*4+r]
#pragma unroll
    for (int js = 0; js < 4; ++js) {
      bf16x4 pk;
#pragma unroll
      for (int r = 0; r < 4; ++r) pk[r] = (bf16)(s[js][r] * (ALPHA_ * SCALE_));
      const int cb = (jb + st * 64 + js * 16 + q4 * 4) * 2;
      *reinterpret_cast<bf16x4*>(srow_w + swz(l16, cb)) = pk;
    }
  }

  // prefetch h rows wv*4+2,3 (fly across the barrier; vmcnt is per-wave)
  float4 hv2[4], hv3[4];
#pragma unroll
  for (int t = 0; t < 4; ++t) {
    hv2[t] = *reinterpret_cast<const float4*>(
        hbase + (size_t)(i0 + wv * 4 + 2) * NSEQ + t * 256 + l * 4);
    hv3[t] = *reinterpret_cast<const float4*>(
        hbase + (size_t)(i0 + wv * 4 + 3) * NSEQ + t * 256 + l * 4);
  }

  BAR_LGKM();  // all waves' S writes visible

  // ---- Phase 2: stream 4 full rows; exact softmax; P overwrites S ----
  auto ROW = [&](int rr, float4* hv) {
    const int row = wv * 4 + rr;
    char* srow = S_lds + row * 2176;
    bf16x4 sv[4];
#pragma unroll
    for (int t = 0; t < 4; ++t)
      sv[t] = *reinterpret_cast<const bf16x4*>(srow + swz(row, t * 512 + l * 8));
    float4 bl[4];
    float tm = -1e30f;
#pragma unroll
    for (int t = 0; t < 4; ++t) {
      bl[t].x = fmaf(0.75f, hv[t].x, (float)sv[t][0]);
      bl[t].y = fmaf(0.75f, hv[t].y, (float)sv[t][1]);
      bl[t].z = fmaf(0.75f, hv[t].z, (float)sv[t][2]);
      bl[t].w = fmaf(0.75f, hv[t].w, (float)sv[t][3]);
      *reinterpret_cast<float4*>(
          bbase + (size_t)(i0 + row) * NSEQ + t * 256 + l * 4) = bl[t];
      tm = fmaxf(tm, fmaxf(fmaxf(bl[t].x, bl[t].y), fmaxf(bl[t].z, bl[t].w)));
    }
#pragma unroll
    for (int mm = 1; mm < 64; mm <<= 1) tm = fmaxf(tm, __shfl_xor(tm, mm));
    float rs = 0.f;
#pragma unroll
    for (int t = 0; t < 4; ++t) {
      bf16x4 pk;
      const float p0 = __expf(bl[t].x - tm); rs += p0; pk[0] = (bf16)p0;
      const float p1 = __expf(bl[t].y - tm); rs += p1; pk[1] = (bf16)p1;
      const float p2 = __expf(bl[t].z - tm); rs += p2; pk[2] = (bf16)p2;
      const float p3 = __expf(bl[t].w - tm); rs += p3; pk[3] = (bf16)p3;
      *reinterpret_cast<bf16x4*>(srow + swz(row, t * 512 + l * 8)) = pk;
    }
#pragma unroll
    for (int mm = 1; mm < 64; mm <<= 1) rs += __shfl_xor(rs, mm);
    if (l == 0) lred[row] = rs;
  };
  ROW(0, hv0);
  ROW(1, hv1);
  ROW(2, hv2);
  ROW(3, hv3);

  BAR_LGKM();  // all P + lred visible

  // ---- Phase 3: out(16q x 16d per wave) = P @ V^T ----
  const bf16* vq = vt + ((size_t)bh * DH + wv * 16 + l16) * NSEQ + q4 * 8;
  char* prow = S_lds + l16 * 2176;
  f32x4 a0 = f32x4{0.f, 0.f, 0.f, 0.f}, a1 = a0, a2 = a0, a3 = a0;
#pragma unroll
  for (int ks = 0; ks < 32; ks += 4) {
    const bf16x8 pa0 = *reinterpret_cast<const bf16x8*>(prow + swz(l16, (ks + 0) * 64 + q4 * 16));
    const bf16x8 vf0 = *reinterpret_cast<const bf16x8*>(vq + (ks + 0) * 32);
    a0 = MFMA16(pa0, vf0, a0);
    const bf16x8 pa1 = *reinterpret_cast<const bf16x8*>(prow + swz(l16, (ks + 1) * 64 + q4 * 16));
    const bf16x8 vf1 = *reinterpret_cast<const bf16x8*>(vq + (ks + 1) * 32);
    a1 = MFMA16(pa1, vf1, a1);
    const bf16x8 pa2 = *reinterpret_cast<const bf16x8*>(prow + swz(l16, (ks + 2) * 64 + q4 * 16));
    const bf16x8 vf2 = *reinterpret_cast<const bf16x8*>(vq + (ks + 2) * 32);
    a2 = MFMA16(pa2, vf2, a2);
    const bf16x8 pa3 = *reinterpret_cast<const bf16x8*>(prow + swz(l16, (ks + 3) * 64 + q4 * 16));
    const bf16x8 vf3 = *reinterpret_cast<const bf16x8*>(vq + (ks + 3) * 32);
    a3 = MFMA16(pa3, vf3, a3);
  }
  const f32x4 af = (a0 + a1) + (a2 + a3);
  const int b = bh / NHEADS, head = bh % NHEADS;
#pragma unroll
  for (int r = 0; r < 4; ++r) {
    const int q = q4 * 4 + r;
    attn_out[((size_t)b * NSEQ + i0 + q) * DIMM + head * DH + wv * 16 + l16] =
        (bf16)(af[r] / lred[q]);
  }
}

// -------- output projection: attn_out(8192x768) @ woutT + b_out -> f32 out --------
__global__ __launch_bounds__(256) void oproj_gemm(
    const bf16* __restrict__ ain, const bf16* __restrict__ wT,
    const float* __restrict__ bias, float* __restrict__ out) {
  __shared__ __align__(16) bf16 As[128 * 32];
  __shared__ __align__(16) bf16 Bs[64 * 32];
  const int tid = threadIdx.x;
  const int wv = tid >> 6, l = tid & 63;
  const int l16 = l & 15, q4 = l >> 4;
  const int c0 = blockIdx.x * 64, row0 = blockIdx.y * 128;
  const int sr = tid >> 2, skk = (tid & 3) * 8;
  f32x4 acc0[4], acc1[4];
#pragma unroll
  for (int c = 0; c < 4; ++c) {
    acc0[c] = f32x4{0.f, 0.f, 0.f, 0.f};
    acc1[c] = f32x4{0.f, 0.f, 0.f, 0.f};
  }
  for (int k0 = 0; k0 < DIMM; k0 += 32) {
    __syncthreads();
    load_lds16(ain + (size_t)(row0 + sr) * DIMM + k0 + skk, As + tid * 8);
    load_lds16(ain + (size_t)(row0 + 64 + sr) * DIMM + k0 + skk, As + 2048 + tid * 8);
    load_lds16(wT + (size_t)(c0 + sr) * DIMM + k0 + skk, Bs + tid * 8);
    __syncthreads();
    const bf16x8 a0 = *reinterpret_cast<const bf16x8*>(&As[(wv * 32 + l16) * 32 + q4 * 8]);
    const bf16x8 a1 = *reinterpret_cast<const bf16x8*>(&As[(wv * 32 + 16 + l16) * 32 + q4 * 8]);
#pragma unroll
    for (int c = 0; c < 4; ++c) {
      const bf16x8 bb = *reinterpret_cast<const bf16x8*>(&Bs[(c * 16 + l16) * 32 + q4 * 8]);
      acc0[c] = MFMA16(a0, bb, acc0[c]);
      acc1[c] = MFMA16(a1, bb, acc1[c]);
    }
  }
#pragma unroll
  for (int c = 0; c < 4; ++c) {
    const int gc = c0 + c * 16 + l16;
    const float bv = bias[gc];
#pragma unroll
    for (int r = 0; r < 4; ++r) {
      out[(size_t)(row0 + wv * 32 + q4 * 4 + r) * DIMM + gc] = acc0[c][r] + bv;
      out[(size_t)(row0 + wv * 32 + 16 + q4 * 4 + r) * DIMM + gc] = acc1[c][r] + bv;
    }
  }
}

extern "C" void kernel_launch(void* const* d_in, const int* in_sizes, int n_in,
                              void* d_out, int out_size, void* d_ws, size_t ws_size,
                              hipStream_t stream) {
  const float* x = (const float*)d_in[0];
  const float* h = (const float*)d_in[1];
  const float* gamma = (const float*)d_in[2];
  const float* beta = (const float*)d_in[3];
  const float* w_qkv = (const float*)d_in[4];
  const float* w_out = (const float*)d_in[5];
  const float* b_out = (const float*)d_in[6];
  float* out = (float*)d_out;
  float* blended = out + (size_t)NB * NSEQ * DIMM;

  char* ws = (char*)d_ws;
  bf16* xn = (bf16*)(ws);                   // 12.6 MB; reused as attn_out after qkv_gemm
  bf16* qb = (bf16*)(ws + 12582912);
  bf16* kb = (bf16*)(ws + 25165824);
  bf16* vt = (bf16*)(ws + 37748736);
  bf16* wqkvT = (bf16*)(ws + 50331648);
  bf16* woutT = (bf16*)(ws + 53870592);

  hipLaunchKernelGGL(ln_kernel, dim3(2048), dim3(256), 0, stream, x, gamma, beta, xn);
  hipLaunchKernelGGL(tcast_kernel, dim3(72, 24), dim3(256), 0, stream, w_qkv, wqkvT, DIMM, NQKV);
  hipLaunchKernelGGL(tcast_kernel, dim3(24, 24), dim3(256), 0, stream, w_out, woutT, DIMM, DIMM);
  hipLaunchKernelGGL(qkv_gemm, dim3(36, 64), dim3(256), 0, stream, xn, wqkvT, qb, kb, vt);
  hipLaunchKernelGGL(attn_kernel, dim3(64, 96), dim3(256), 0, stream, qb, kb, vt, h, blended, xn);
  hipLaunchKernelGGL(oproj_gemm, dim3(12, 64), dim3(256), 0, stream, xn, woutT, b_out, out);
}